// Round 3
// baseline (845.327 us; speedup 1.0000x reference)
//
#include <hip/hip_runtime.h>
#include <cstdint>

#define T_LEN 1000
#define NB    256

typedef float v2f __attribute__((ext_vector_type(2)));

__device__ __forceinline__ float rcpf_(float x)     { return __builtin_amdgcn_rcpf(x); }
__device__ __forceinline__ float sigmoidf_(float x) { return rcpf_(1.f + __expf(-x)); }
__device__ __forceinline__ float tanhf_(float x) {
    float e = __expf(2.f * x);
    return 1.f - 2.f * rcpf_(e + 1.f);
}
__device__ __forceinline__ float softplusf_(float x) {
    return fmaxf(x, 0.f) + __logf(1.f + __expf(-fabsf(x)));
}
__device__ __forceinline__ float bcast_(float v, int l) {
    return __uint_as_float(__builtin_amdgcn_readlane(__float_as_uint(v), l));
}
__device__ __forceinline__ v2f pkfma_(v2f a, v2f b, v2f c) {
    v2f d;
    asm("v_pk_fma_f32 %0, %1, %2, %3" : "=v"(d) : "v"(a), "v"(b), "v"(c));
    return d;
}

// ---------------- K1: gi2 = mini_batch @ W_ih2^T + b_ih2  -> out[b,t,0:30] (scratch) --------
__global__ __launch_bounds__(256) void gi2_kernel(
    const float* __restrict__ x, const float* __restrict__ W,
    const float* __restrict__ bias, float* __restrict__ out)
{
    __shared__ float xsT[100 * 67];          // xsT[k*67 + r], 26.8 KB

    const int tid = threadIdx.x;
    const int64_t base = (int64_t)blockIdx.x * (64 * 100);
    const float4* gx = (const float4*)(x + base);

#pragma unroll
    for (int it = 0; it < 7; ++it) {
        int i = tid + it * 256;
        if (i < 1600) {
            int r  = i / 25;
            int k4 = i - r * 25;
            float4 v = gx[i];                 // coalesced 16B/lane
            xsT[(4 * k4 + 0) * 67 + r] = v.x;
            xsT[(4 * k4 + 1) * 67 + r] = v.y;
            xsT[(4 * k4 + 2) * 67 + r] = v.z;
            xsT[(4 * k4 + 3) * 67 + r] = v.w;
        }
    }
    __syncthreads();

    const int lane = tid & 63;                               // row within tile
    const int wv   = __builtin_amdgcn_readfirstlane(tid >> 6);
    const int j0   = wv * 8;                                 // 8 output cols per wave

    float acc[8];
#pragma unroll
    for (int jj = 0; jj < 8; ++jj) acc[jj] = 0.f;

    for (int k = 0; k < 100; ++k) {
        float xv = xsT[k * 67 + lane];
#pragma unroll
        for (int jj = 0; jj < 8; ++jj) {
            int j = j0 + jj; j = j > 29 ? 29 : j;            // wave-uniform -> s_load
            acc[jj] = fmaf(xv, W[j * 100 + k], acc[jj]);
        }
    }
    float* orow = out + base + (int64_t)lane * 100;
#pragma unroll
    for (int jj = 0; jj < 8; ++jj) {
        int j = j0 + jj;
        if (j < 30) orow[j] = acc[jj] + bias[j];
    }
}

// ---------------- K2: sequential scan. 1 block / batch element, 2 waves ---------------------
// wave0: h1 critical chain.  wave1: h2 GRU + emitter (lagged 1 step) + stores.
// z layout: lane k owns z[2k], z[2k+1]; LDS ss[] holds z in natural order with 16B-aligned
// halves at ss[0..51] (z0..49 + pad) and ss[52..103] (z50..99 + pad).
__global__ __launch_bounds__(128) void scan_kernel(
    const float* __restrict__ eps,
    const float* __restrict__ W_ih1, const float* __restrict__ W_hh1,
    const float* __restrict__ b_ih1, const float* __restrict__ b_hh1,
    const float* __restrict__ W_hh2, const float* __restrict__ b_hh2,
    const float* __restrict__ h1_0,  const float* __restrict__ h2_0,
    const float* __restrict__ Wt1,   const float* __restrict__ bt1,
    const float* __restrict__ Wloc,  const float* __restrict__ bloc,
    const float* __restrict__ Wsc,   const float* __restrict__ bsc,
    const float* __restrict__ We1,   const float* __restrict__ be1,
    const float* __restrict__ We2,   const float* __restrict__ be2,
    const float* __restrict__ We3,   const float* __restrict__ be3,
    float* out)
{
    __shared__ __align__(16) float ss[104];          // z-tilde, padded halves
    __shared__ __align__(16) float sh1ring[2][12];   // h1 after step t -> slot t&1 (w0 -> w1)

    const int lane = threadIdx.x & 63;
    const int64_t rowbase = (int64_t)blockIdx.x * T_LEN * 100;
    const int wave = __builtin_amdgcn_readfirstlane((int)(threadIdx.x >> 6));

    if (wave == 0) {
        // ================= wave0: h1 chain =================
        const int j   = lane & 31;
        const int jc  = j < 30 ? j : 29;       // clamped row (garbage lanes unused)
        const int h   = lane >> 5;             // k-half for the 100-deep gi1 reduction
        const int lt  = lane < 20 ? lane : 19;
        const int k50 = lane < 50 ? lane : 49; // z pair index

        float wt1r[10], whh1r[10], Cr[20];
        v2f wsc2[20], wbig2[26];
#pragma unroll
        for (int k = 0; k < 10; ++k) {
            wt1r[k]  = Wt1[lt * 10 + k];
            whh1r[k] = W_hh1[jc * 10 + k];
        }
        float bt1r  = bt1[lt];
        float bhh1r = b_hh1[jc];
        float br1   = b_ih1[jc];
#pragma unroll
        for (int l = 0; l < 20; ++l) {
            wsc2[l].x = Wsc[(2 * k50)     * 20 + l];
            wsc2[l].y = Wsc[(2 * k50 + 1) * 20 + l];
        }
        float bscx = bsc[2 * k50], bscy = bsc[2 * k50 + 1];
#pragma unroll
        for (int c = 0; c < 13; ++c) {
#pragma unroll
            for (int d = 0; d < 2; ++d) {
                int i0 = 4 * c + 2 * d;
                v2f w; w.x = 0.f; w.y = 0.f;
                if (i0     < 50) w.x = W_ih1[jc * 100 + 50 * h + i0];
                if (i0 + 1 < 50) w.y = W_ih1[jc * 100 + 50 * h + i0 + 1];
                wbig2[2 * c + d] = w;
            }
        }

        // one-off fold: Cr[l] = (W_ih1 @ Wloc)[jc][l],  dr = (W_ih1 @ bloc)[jc]
        float dr = 0.f;
#pragma unroll
        for (int l = 0; l < 20; ++l) Cr[l] = 0.f;
        for (int kk = 0; kk < 100; ++kk) {
            float w = W_ih1[jc * 100 + kk];
            dr = fmaf(w, bloc[kk], dr);
#pragma unroll
            for (int l = 0; l < 20; ++l) Cr[l] = fmaf(w, Wloc[kk * 20 + l], Cr[l]);
        }

        if (lane < 2) { ss[50 + lane] = 0.f; ss[102 + lane] = 0.f; }   // zero pads

        float h1keep = h1_0[lane < 10 ? lane : 0];
        float sh1_[10];
#pragma unroll
        for (int k = 0; k < 10; ++k) sh1_[k] = h1_0[k];

        const float* erow = eps + rowbase;
        const int sidx = 2 * k50 + (k50 >= 25 ? 2 : 0);
        v2f ecur = *(const v2f*)(erow + 2 * k50);
        v2f enxt = *(const v2f*)(erow + 100 + 2 * k50);

#pragma unroll 1
        for (int t = 0; t <= T_LEN; ++t) {
            if (t < T_LEN) {
                // prefetch eps(t+2): in flight ~2 full steps
                v2f efut; efut.x = 0.f; efut.y = 0.f;
                if (t + 2 < T_LEN)
                    efut = *(const v2f*)(erow + (int64_t)(t + 2) * 100 + 2 * k50);

                // hid + gh1 from SGPR-resident h1 (2 accumulators each)
                float ha = bt1r, hb = 0.f, ga = bhh1r, gb = 0.f;
#pragma unroll
                for (int k = 0; k < 5; ++k) {
                    ha = fmaf(wt1r[2 * k],      sh1_[2 * k],     ha);
                    hb = fmaf(wt1r[2 * k + 1],  sh1_[2 * k + 1], hb);
                    ga = fmaf(whh1r[2 * k],     sh1_[2 * k],     ga);
                    gb = fmaf(whh1r[2 * k + 1], sh1_[2 * k + 1], gb);
                }
                float hidv = fmaxf(ha + hb, 0.f);
                float gh1v = ga + gb;

                float sgh[20];
#pragma unroll
                for (int l = 0; l < 20; ++l) sgh[l] = bcast_(hidv, l);

                // sc pair + folded loc term gq (2 accumulators per chain)
                float sA0 = bscx, sA1 = 0.f, sB0 = bscy, sB1 = 0.f, q0 = dr, q1 = 0.f;
#pragma unroll
                for (int l = 0; l < 10; ++l) {
                    sA0 = fmaf(wsc2[2 * l].x,     sgh[2 * l],     sA0);
                    sA1 = fmaf(wsc2[2 * l + 1].x, sgh[2 * l + 1], sA1);
                    sB0 = fmaf(wsc2[2 * l].y,     sgh[2 * l],     sB0);
                    sB1 = fmaf(wsc2[2 * l + 1].y, sgh[2 * l + 1], sB1);
                    q0  = fmaf(Cr[2 * l],         sgh[2 * l],     q0);
                    q1  = fmaf(Cr[2 * l + 1],     sgh[2 * l + 1], q1);
                }
                float gq = q0 + q1;
                float zx = softplusf_(sA0 + sA1) * ecur.x;
                float zy = softplusf_(sB0 + sB1) * ecur.y;
                if (lane < 50) {
                    v2f zp; zp.x = zx; zp.y = zy;
                    *(v2f*)(&ss[sidx]) = zp;
                }
                ecur = enxt; enxt = efut;
                __builtin_amdgcn_wave_barrier();

                // gi1 partial: 52-elem dot over own k-half via packed-f32 FMA
                const float4* sp4 = (const float4*)(&ss[52 * h]);
                v2f a0; a0.x = 0.f; a0.y = 0.f;
                v2f a1 = a0;
#pragma unroll
                for (int c = 0; c < 13; ++c) {
                    float4 v = sp4[c];
                    v2f vlo; vlo.x = v.x; vlo.y = v.y;
                    v2f vhi; vhi.x = v.z; vhi.y = v.w;
                    a0 = pkfma_(wbig2[2 * c],     vlo, a0);
                    a1 = pkfma_(wbig2[2 * c + 1], vhi, a1);
                }
                float p = (a0.x + a0.y) + (a1.x + a1.y);
                float gi1v = p + __shfl_xor(p, 32) + br1 + gq;
                float av   = gi1v + gh1v;
                float a10  = __shfl(av,   lane + 10);
                float gin  = __shfl(gi1v, lane + 20);
                float ghn  = __shfl(gh1v, lane + 20);
                if (lane < 10) {
                    float r = sigmoidf_(av);
                    float u = sigmoidf_(a10);
                    float n = tanhf_(fmaf(r, ghn, gin));
                    h1keep = fmaf(u, h1keep - n, n);       // (1-u)*n + u*h1
                    sh1ring[t & 1][lane] = h1keep;          // hand-off to wave1
                }
#pragma unroll
                for (int k = 0; k < 10; ++k) sh1_[k] = bcast_(h1keep, k);
            }
            __syncthreads();
        }
    } else {
        // ================= wave1: h2 chain (SGPR state) + emitter(t-1) =================
        const int lt20 = lane < 20 ? lane : 19;
        const int l30  = lane < 30 ? lane : 29;
        const int ls   = lane < 50 ? lane : 49;

        float whh2r[10];
#pragma unroll
        for (int k = 0; k < 10; ++k) whh2r[k] = W_hh2[l30 * 10 + k];
        float bhh2r = b_hh2[l30];

        float we1r[20], we2r[20], we3A[20], we3B[20];
#pragma unroll
        for (int k = 0; k < 20; ++k) {
            we1r[k] = We1[lt20 * 20 + k];
            we2r[k] = We2[lt20 * 20 + k];
            we3A[k] = We3[ls * 20 + k];
            we3B[k] = We3[(ls + 50) * 20 + k];
        }
        float be1r = be1[lt20], be2r = be2[lt20];
        float be3A = be3[ls],   be3B = be3[ls + 50];

        float h2keep = h2_0[lane < 10 ? lane : 0];
        float g2c[10], g2p[10];                  // H2(t), H2(t-1) as broadcast scalars
#pragma unroll
        for (int k = 0; k < 10; ++k) { g2c[k] = h2_0[k]; g2p[k] = h2_0[k]; }

        float gcur = out[rowbase + l30];                 // gi2(0)
        float gnxt = out[rowbase + 100 + l30];           // gi2(1)

#pragma unroll 1
        for (int t = 0; t <= T_LEN; ++t) {
            // prefetch gi2(t+2): in flight ~2 full steps
            float gfut = 0.f;
            if (t + 2 < T_LEN)
                gfut = out[rowbase + (int64_t)(t + 2) * 100 + l30];

            // early h1(t-1) read for emitter (latency hidden under h2 GRU)
            float4 d0 = make_float4(0.f, 0.f, 0.f, 0.f);
            float4 d1 = d0; float d8 = 0.f, d9 = 0.f;
            if (t >= 1) {
                const int s1 = (t - 1) & 1;
                d0 = *(const float4*)(&sh1ring[s1][0]);
                d1 = *(const float4*)(&sh1ring[s1][4]);
                d8 = sh1ring[s1][8]; d9 = sh1ring[s1][9];
            }

            const bool upd = (t < T_LEN);
            if (upd) {
                float ga = bhh2r, gb = 0.f;
#pragma unroll
                for (int k = 0; k < 5; ++k) {
                    ga = fmaf(whh2r[2 * k],     g2c[2 * k],     ga);
                    gb = fmaf(whh2r[2 * k + 1], g2c[2 * k + 1], gb);
                }
                float gh2v = ga + gb;
                float gi2v = gcur;
                gcur = gnxt; gnxt = gfut;
                float a2  = gi2v + gh2v;
                float a10 = __shfl(a2,   lane + 10);
                float gin = __shfl(gi2v, lane + 20);
                float ghn = __shfl(gh2v, lane + 20);
                if (lane < 10) {
                    float r = sigmoidf_(a2);
                    float u = sigmoidf_(a10);
                    float n = tanhf_(fmaf(r, ghn, gin));
                    h2keep = fmaf(u, h2keep - n, n);       // H2(t+1)
                }
            }

            if (t >= 1) {
                // emitter step s = t-1: h1(s) from LDS, H2(s)=g2p broadcast
                float ea = be1r, eb = 0.f;
                ea = fmaf(we1r[0], d0.x, ea); eb = fmaf(we1r[1], d0.y, eb);
                ea = fmaf(we1r[2], d0.z, ea); eb = fmaf(we1r[3], d0.w, eb);
                ea = fmaf(we1r[4], d1.x, ea); eb = fmaf(we1r[5], d1.y, eb);
                ea = fmaf(we1r[6], d1.z, ea); eb = fmaf(we1r[7], d1.w, eb);
                ea = fmaf(we1r[8], d8,   ea); eb = fmaf(we1r[9], d9,   eb);
#pragma unroll
                for (int k = 0; k < 5; ++k) {
                    ea = fmaf(we1r[10 + 2 * k],     g2p[2 * k],     ea);
                    eb = fmaf(we1r[10 + 2 * k + 1], g2p[2 * k + 1], eb);
                }
                float e1v = fmaxf(ea + eb, 0.f);

                float se1v[20];
#pragma unroll
                for (int l = 0; l < 20; ++l) se1v[l] = bcast_(e1v, l);

                float fa = be2r, fb = 0.f;
#pragma unroll
                for (int k = 0; k < 10; ++k) {
                    fa = fmaf(we2r[2 * k],     se1v[2 * k],     fa);
                    fb = fmaf(we2r[2 * k + 1], se1v[2 * k + 1], fb);
                }
                float e2v = fmaxf(fa + fb, 0.f);

                float se2v[20];
#pragma unroll
                for (int l = 0; l < 20; ++l) se2v[l] = bcast_(e2v, l);

                float xa0 = be3A, xa1 = 0.f, xb0 = be3B, xb1 = 0.f;
#pragma unroll
                for (int l = 0; l < 10; ++l) {
                    xa0 = fmaf(we3A[2 * l],     se2v[2 * l],     xa0);
                    xa1 = fmaf(we3A[2 * l + 1], se2v[2 * l + 1], xa1);
                    xb0 = fmaf(we3B[2 * l],     se2v[2 * l],     xb0);
                    xb1 = fmaf(we3B[2 * l + 1], se2v[2 * l + 1], xb1);
                }
                float xA = sigmoidf_(xa0 + xa1);
                float xB = sigmoidf_(xb0 + xb1);
                if (lane < 50) {
                    int64_t ro = rowbase + (int64_t)(t - 1) * 100;
                    out[ro + lane]      = xA;
                    out[ro + lane + 50] = xB;
                }
            }

            if (upd) {
#pragma unroll
                for (int k = 0; k < 10; ++k) g2p[k] = g2c[k];
#pragma unroll
                for (int k = 0; k < 10; ++k) g2c[k] = bcast_(h2keep, k);
            }
            __syncthreads();
        }
    }
}

extern "C" void kernel_launch(void* const* d_in, const int* in_sizes, int n_in,
                              void* d_out, int out_size, void* d_ws, size_t ws_size,
                              hipStream_t stream) {
    const float* mini_batch = (const float*)d_in[0];
    const float* eps        = (const float*)d_in[1];
    const float* W_ih1      = (const float*)d_in[2];
    const float* W_hh1      = (const float*)d_in[3];
    const float* b_ih1      = (const float*)d_in[4];
    const float* b_hh1      = (const float*)d_in[5];
    const float* W_ih2      = (const float*)d_in[6];
    const float* W_hh2      = (const float*)d_in[7];
    const float* b_ih2      = (const float*)d_in[8];
    const float* b_hh2      = (const float*)d_in[9];
    const float* h1_0       = (const float*)d_in[10];
    const float* h2_0       = (const float*)d_in[11];
    const float* Wt1        = (const float*)d_in[12];
    const float* bt1        = (const float*)d_in[13];
    const float* Wloc       = (const float*)d_in[14];
    const float* bloc       = (const float*)d_in[15];
    const float* Wsc        = (const float*)d_in[16];
    const float* bsc        = (const float*)d_in[17];
    const float* We1        = (const float*)d_in[18];
    const float* be1        = (const float*)d_in[19];
    const float* We2        = (const float*)d_in[20];
    const float* be2        = (const float*)d_in[21];
    const float* We3        = (const float*)d_in[22];
    const float* be3        = (const float*)d_in[23];
    float* out = (float*)d_out;

    // K1: gi2 precompute into out[.., 0:30] (scratch region, overwritten later by K2)
    gi2_kernel<<<(NB * T_LEN) / 64, 256, 0, stream>>>(mini_batch, W_ih2, b_ih2, out);

    // K2: sequential scan, one block per batch element
    scan_kernel<<<NB, 128, 0, stream>>>(eps, W_ih1, W_hh1, b_ih1, b_hh1, W_hh2, b_hh2,
                                        h1_0, h2_0, Wt1, bt1, Wloc, bloc, Wsc, bsc,
                                        We1, be1, We2, be2, We3, be3, out);
}